// Round 1
// baseline (535.984 us; speedup 1.0000x reference)
//
#include <hip/hip_runtime.h>

#define NB   4
#define NN   512
#define NH   12
#define DHD  64
#define HID  768
#define NE   65536
#define NSEG 2048

__device__ __forceinline__ float readlane_f(float v, int lane) {
    return __int_as_float(__builtin_amdgcn_readlane(__float_as_int(v), lane));
}

// ---------------------------------------------------------------------------
// K1: fused QKV projection. Y = X @ W^T + b for W in {Wq,Wk,Wv} (blockIdx.z).
// 64x64 output tile per 256-thread block, 4x4 microtile, K-tile 16,
// LDS tiles stored transposed [kk][m] (pad 68) so microtile reads are b128.
// ---------------------------------------------------------------------------
__global__ __launch_bounds__(256) void qkv_gemm(
    const float* __restrict__ X,
    const float* __restrict__ Wq, const float* __restrict__ bq,
    const float* __restrict__ Wk, const float* __restrict__ bk,
    const float* __restrict__ Wv, const float* __restrict__ bv,
    float* __restrict__ Qo, float* __restrict__ Ko, float* __restrict__ Vo)
{
    const float* W; const float* bias; float* Y;
    if (blockIdx.z == 0)      { W = Wq; bias = bq; Y = Qo; }
    else if (blockIdx.z == 1) { W = Wk; bias = bk; Y = Ko; }
    else                      { W = Wv; bias = bv; Y = Vo; }

    const int n0 = blockIdx.x * 64;
    const int m0 = blockIdx.y * 64;
    const int tid = threadIdx.x;
    const int tx = tid & 15, ty = tid >> 4;

    __shared__ float As[16][68];
    __shared__ float Bs[16][68];

    float c[4][4];
    #pragma unroll
    for (int i = 0; i < 4; ++i)
        #pragma unroll
        for (int j = 0; j < 4; ++j) c[i][j] = 0.f;

    for (int k0 = 0; k0 < HID; k0 += 16) {
        __syncthreads();
        #pragma unroll
        for (int i = 0; i < 4; ++i) {
            const int linear = tid + i * 256;
            const int m  = linear >> 4;
            const int kk = linear & 15;
            As[kk][m] = X[(size_t)(m0 + m) * HID + k0 + kk];
            Bs[kk][m] = W[(size_t)(n0 + m) * HID + k0 + kk];
        }
        __syncthreads();
        #pragma unroll
        for (int kk = 0; kk < 16; ++kk) {
            const float4 a = *(const float4*)&As[kk][ty * 4];
            const float4 b = *(const float4*)&Bs[kk][tx * 4];
            const float av[4] = {a.x, a.y, a.z, a.w};
            const float bw[4] = {b.x, b.y, b.z, b.w};
            #pragma unroll
            for (int i = 0; i < 4; ++i)
                #pragma unroll
                for (int j = 0; j < 4; ++j)
                    c[i][j] = fmaf(av[i], bw[j], c[i][j]);
        }
    }

    const float4 bb = *(const float4*)&bias[n0 + tx * 4];
    const float bias4[4] = {bb.x, bb.y, bb.z, bb.w};
    #pragma unroll
    for (int i = 0; i < 4; ++i) {
        const int m = m0 + ty * 4 + i;
        float4 r;
        r.x = c[i][0] + bias4[0];
        r.y = c[i][1] + bias4[1];
        r.z = c[i][2] + bias4[2];
        r.w = c[i][3] + bias4[3];
        *(float4*)&Y[(size_t)m * HID + n0 + tx * 4] = r;
    }
}

// ---------------------------------------------------------------------------
// K2-K4: CSR bucketing of edges by segment (b*N + head_node)
// ---------------------------------------------------------------------------
__global__ void hist_kernel(const int* __restrict__ ei, int* __restrict__ count)
{
    const int e = blockIdx.x * 256 + threadIdx.x;
    const int b  = ei[e];
    const int hn = ei[NE + e];
    atomicAdd(&count[b * NN + hn], 1);
}

__global__ void scan_kernel(const int* __restrict__ count, int* __restrict__ offs)
{
    __shared__ int buf[256];
    const int tid = threadIdx.x;
    int local[8];
    int s = 0;
    #pragma unroll
    for (int i = 0; i < 8; ++i) { local[i] = count[tid * 8 + i]; s += local[i]; }
    buf[tid] = s;
    __syncthreads();
    for (int off = 1; off < 256; off <<= 1) {
        const int v = (tid >= off) ? buf[tid - off] : 0;
        __syncthreads();
        buf[tid] += v;
        __syncthreads();
    }
    int run = buf[tid] - s;   // exclusive prefix of this thread's chunk
    #pragma unroll
    for (int i = 0; i < 8; ++i) { offs[tid * 8 + i] = run; run += local[i]; }
    if (tid == 255) offs[NSEG] = run;
}

__global__ void scatter_kernel(const int* __restrict__ ei, const int* __restrict__ offs,
                               int* __restrict__ cursor,
                               int* __restrict__ s_te, int* __restrict__ s_re)
{
    const int e = blockIdx.x * 256 + threadIdx.x;
    const int b  = ei[e];
    const int hn = ei[NE + e];
    const int tn = ei[2 * NE + e];
    const int rr = ei[3 * NE + e];
    const int seg = b * NN + hn;
    const int pos = atomicAdd(&cursor[seg], 1);
    const int idx = offs[seg] + pos;
    s_te[idx] = tn;
    s_re[idx] = rr;
}

// ---------------------------------------------------------------------------
// K5: one block (256 thr = 4 waves) per segment. Flash-style online softmax
// over edge chunks of 64. Per wave-edge: lane = k, acc[h] = Qp[h,k] via
// readlane broadcast of block-uniform Q; logits = reduce(acc*K); aggregate
// out += p~ * V with per-head rescale. No global atomics.
// ---------------------------------------------------------------------------
__global__ __launch_bounds__(256) void seg_attn(
    const float* __restrict__ Q, const float* __restrict__ K, const float* __restrict__ V,
    const float* __restrict__ rel,
    const int* __restrict__ offs, const int* __restrict__ s_te, const int* __restrict__ s_re,
    float* __restrict__ out)
{
    const int seg  = blockIdx.x;
    const int tid  = threadIdx.x;
    const int lane = tid & 63;
    const int wave = tid >> 6;
    const int start = offs[seg];
    const int cnt   = offs[seg + 1] - start;
    const int browbase = seg & ~(NN - 1);   // b*N

    __shared__ float lg[64 * NH];
    __shared__ int   te_s[64];
    __shared__ int   re_s[64];
    __shared__ float mh[NH], lh[NH], ah[NH];

    if (tid < NH) { mh[tid] = -1e30f; lh[tid] = 0.f; }

    float q[NH];
    {
        const float* Qi = Q + (size_t)seg * HID;
        #pragma unroll
        for (int h = 0; h < NH; ++h) q[h] = Qi[h * 64 + lane];
    }

    float acc0 = 0.f, acc1 = 0.f, acc2 = 0.f;
    const int hh = tid >> 6;   // 0..3; acc0->h=hh, acc1->h=4+hh, acc2->h=8+hh
    const int dd = tid & 63;

    for (int c0 = 0; c0 < cnt; c0 += 64) {
        const int cc = min(64, cnt - c0);
        __syncthreads();   // protect lg/te_s from previous chunk's readers
        if (tid < cc) {
            te_s[tid] = s_te[start + c0 + tid];
            re_s[tid] = s_re[start + c0 + tid];
        }
        __syncthreads();

        // ---- logits: one edge per wave ----
        for (int j = wave; j < cc; j += 4) {
            const int te = te_s[j];
            const int re = re_s[j];
            const float* __restrict__ Re = rel + (size_t)re * (DHD * DHD);
            float acc[NH];
            #pragma unroll
            for (int h = 0; h < NH; ++h) acc[h] = 0.f;
            for (int d = 0; d < 64; d += 4) {
                const float rv0 = Re[(d + 0) * 64 + lane];
                const float rv1 = Re[(d + 1) * 64 + lane];
                const float rv2 = Re[(d + 2) * 64 + lane];
                const float rv3 = Re[(d + 3) * 64 + lane];
                #pragma unroll
                for (int h = 0; h < NH; ++h) {
                    acc[h] = fmaf(readlane_f(q[h], d + 0), rv0, acc[h]);
                    acc[h] = fmaf(readlane_f(q[h], d + 1), rv1, acc[h]);
                    acc[h] = fmaf(readlane_f(q[h], d + 2), rv2, acc[h]);
                    acc[h] = fmaf(readlane_f(q[h], d + 3), rv3, acc[h]);
                }
            }
            const float* __restrict__ Krow = K + (size_t)(browbase + te) * HID;
            #pragma unroll
            for (int h = 0; h < NH; ++h) {
                float s = acc[h] * Krow[h * 64 + lane];
                s += __shfl_xor(s, 1, 64);
                s += __shfl_xor(s, 2, 64);
                s += __shfl_xor(s, 4, 64);
                s += __shfl_xor(s, 8, 64);
                s += __shfl_xor(s, 16, 64);
                s += __shfl_xor(s, 32, 64);
                if (lane == 0) lg[j * NH + h] = s * 0.125f;
            }
        }
        __syncthreads();

        // ---- online softmax state update (12 threads, one per head) ----
        if (tid < NH) {
            const int h = tid;
            float mx = mh[h];
            for (int j = 0; j < cc; ++j) mx = fmaxf(mx, lg[j * NH + h]);
            const float alpha = __expf(mh[h] - mx);
            float ssum = 0.f;
            for (int j = 0; j < cc; ++j) {
                const float p = __expf(lg[j * NH + h] - mx);
                lg[j * NH + h] = p;
                ssum += p;
            }
            lh[h] = lh[h] * alpha + ssum;
            mh[h] = mx;
            ah[h] = alpha;
        }
        __syncthreads();

        // ---- aggregate: each thread owns 3 output floats ----
        const float a0 = ah[hh], a1 = ah[4 + hh], a2 = ah[8 + hh];
        acc0 *= a0; acc1 *= a1; acc2 *= a2;
        for (int j = 0; j < cc; ++j) {
            const int row = browbase + te_s[j];
            const float* __restrict__ Vr = V + (size_t)row * HID + dd;
            acc0 = fmaf(lg[j * NH + hh],     Vr[hh * 64],       acc0);
            acc1 = fmaf(lg[j * NH + 4 + hh], Vr[(4 + hh) * 64], acc1);
            acc2 = fmaf(lg[j * NH + 8 + hh], Vr[(8 + hh) * 64], acc2);
        }
    }
    __syncthreads();

    const float l0 = lh[hh], l1 = lh[4 + hh], l2 = lh[8 + hh];
    float* Yo = out + (size_t)seg * HID;
    Yo[tid]       = (l0 > 0.f) ? acc0 / l0 : 0.f;
    Yo[tid + 256] = (l1 > 0.f) ? acc1 / l1 : 0.f;
    Yo[tid + 512] = (l2 > 0.f) ? acc2 / l2 : 0.f;
}

// ---------------------------------------------------------------------------
extern "C" void kernel_launch(void* const* d_in, const int* in_sizes, int n_in,
                              void* d_out, int out_size, void* d_ws, size_t ws_size,
                              hipStream_t stream)
{
    const float* X   = (const float*)d_in[0];
    const int*   EI  = (const int*)d_in[1];
    const float* Wq  = (const float*)d_in[3];
    const float* bq  = (const float*)d_in[4];
    const float* Wk  = (const float*)d_in[5];
    const float* bk  = (const float*)d_in[6];
    const float* Wv  = (const float*)d_in[7];
    const float* bv  = (const float*)d_in[8];
    const float* rel = (const float*)d_in[9];
    float* out = (float*)d_out;

    // workspace layout (~18.6 MB)
    float* Qb = (float*)d_ws;
    float* Kb = Qb + (size_t)NB * NN * HID;
    float* Vb = Kb + (size_t)NB * NN * HID;
    int* offs   = (int*)(Vb + (size_t)NB * NN * HID);  // NSEG+1 (padded to 2112)
    int* count  = offs + 2112;
    int* cursor = count + NSEG;
    int* s_te   = cursor + NSEG;
    int* s_re   = s_te + NE;

    qkv_gemm<<<dim3(HID / 64, (NB * NN) / 64, 3), 256, 0, stream>>>(
        X, Wq, bq, Wk, bk, Wv, bv, Qb, Kb, Vb);

    hipMemsetAsync(count, 0, 2 * NSEG * sizeof(int), stream);  // count + cursor
    hist_kernel<<<NE / 256, 256, 0, stream>>>(EI, count);
    scan_kernel<<<1, 256, 0, stream>>>(count, offs);
    scatter_kernel<<<NE / 256, 256, 0, stream>>>(EI, offs, cursor, s_te, s_re);

    seg_attn<<<NSEG, 256, 0, stream>>>(Qb, Kb, Vb, rel, offs, s_te, s_re, out);
}

// Round 2
// 434.012 us; speedup vs baseline: 1.2350x; 1.2350x over previous
//
#include <hip/hip_runtime.h>
#include <hip/hip_bf16.h>

#define NB   4
#define NN   512
#define NH   12
#define DHD  64
#define HID  768
#define NE   65536
#define NSEG 2048
#define NREL 64

typedef short bf16x8 __attribute__((ext_vector_type(8)));
typedef float f32x4  __attribute__((ext_vector_type(4)));

__device__ __forceinline__ unsigned short f2bf(float f) {
    __hip_bfloat16 h = __float2bfloat16(f);
    return *reinterpret_cast<unsigned short*>(&h);
}
__device__ __forceinline__ float bf2f(short s) {
    return __int_as_float(((int)(unsigned short)s) << 16);
}

// ---------------------------------------------------------------------------
// K1: fused QKV projection. z=0 -> Qh (bf16), z=1 -> Kh (bf16), z=2 -> V (f32)
// ---------------------------------------------------------------------------
__global__ __launch_bounds__(256) void qkv_gemm(
    const float* __restrict__ X,
    const float* __restrict__ Wq, const float* __restrict__ bq,
    const float* __restrict__ Wk, const float* __restrict__ bk,
    const float* __restrict__ Wv, const float* __restrict__ bv,
    __hip_bfloat16* __restrict__ Qh, __hip_bfloat16* __restrict__ Kh,
    float* __restrict__ Vo)
{
    const float* W; const float* bias;
    if (blockIdx.z == 0)      { W = Wq; bias = bq; }
    else if (blockIdx.z == 1) { W = Wk; bias = bk; }
    else                      { W = Wv; bias = bv; }

    const int n0 = blockIdx.x * 64;
    const int m0 = blockIdx.y * 64;
    const int tid = threadIdx.x;
    const int tx = tid & 15, ty = tid >> 4;

    __shared__ float As[16][68];
    __shared__ float Bs[16][68];

    float c[4][4];
    #pragma unroll
    for (int i = 0; i < 4; ++i)
        #pragma unroll
        for (int j = 0; j < 4; ++j) c[i][j] = 0.f;

    for (int k0 = 0; k0 < HID; k0 += 16) {
        __syncthreads();
        #pragma unroll
        for (int i = 0; i < 4; ++i) {
            const int linear = tid + i * 256;
            const int m  = linear >> 4;
            const int kk = linear & 15;
            As[kk][m] = X[(size_t)(m0 + m) * HID + k0 + kk];
            Bs[kk][m] = W[(size_t)(n0 + m) * HID + k0 + kk];
        }
        __syncthreads();
        #pragma unroll
        for (int kk = 0; kk < 16; ++kk) {
            const float4 a = *(const float4*)&As[kk][ty * 4];
            const float4 b = *(const float4*)&Bs[kk][tx * 4];
            const float av[4] = {a.x, a.y, a.z, a.w};
            const float bw[4] = {b.x, b.y, b.z, b.w};
            #pragma unroll
            for (int i = 0; i < 4; ++i)
                #pragma unroll
                for (int j = 0; j < 4; ++j)
                    c[i][j] = fmaf(av[i], bw[j], c[i][j]);
        }
    }

    const float4 bb = *(const float4*)&bias[n0 + tx * 4];
    const float bias4[4] = {bb.x, bb.y, bb.z, bb.w};
    if (blockIdx.z == 2) {
        #pragma unroll
        for (int i = 0; i < 4; ++i) {
            const int m = m0 + ty * 4 + i;
            float4 r;
            r.x = c[i][0] + bias4[0];
            r.y = c[i][1] + bias4[1];
            r.z = c[i][2] + bias4[2];
            r.w = c[i][3] + bias4[3];
            *(float4*)&Vo[(size_t)m * HID + n0 + tx * 4] = r;
        }
    } else {
        __hip_bfloat16* Y = (blockIdx.z == 0) ? Qh : Kh;
        #pragma unroll
        for (int i = 0; i < 4; ++i) {
            const int m = m0 + ty * 4 + i;
            ushort4 r;
            r.x = f2bf(c[i][0] + bias4[0]);
            r.y = f2bf(c[i][1] + bias4[1]);
            r.z = f2bf(c[i][2] + bias4[2]);
            r.w = f2bf(c[i][3] + bias4[3]);
            *(ushort4*)&Y[(size_t)m * HID + n0 + tx * 4] = r;
        }
    }
}

// ---------------------------------------------------------------------------
// CSR build: histogram by segment AND by relation, scan both, scatter both.
// ---------------------------------------------------------------------------
__global__ void hist_kernel(const int* __restrict__ ei,
                            int* __restrict__ count, int* __restrict__ rcount)
{
    const int e = blockIdx.x * 256 + threadIdx.x;
    const int b  = ei[e];
    const int hn = ei[NE + e];
    const int rr = ei[3 * NE + e];
    atomicAdd(&count[b * NN + hn], 1);
    atomicAdd(&rcount[rr], 1);
}

__global__ void scan_kernel(const int* __restrict__ count, int* __restrict__ offs,
                            const int* __restrict__ rcount, int* __restrict__ rofs)
{
    __shared__ int buf[256];
    const int tid = threadIdx.x;
    if (tid == 0) {
        int run = 0;
        for (int i = 0; i < NREL; ++i) { rofs[i] = run; run += rcount[i]; }
        rofs[NREL] = run;
    }
    int local[8];
    int s = 0;
    #pragma unroll
    for (int i = 0; i < 8; ++i) { local[i] = count[tid * 8 + i]; s += local[i]; }
    buf[tid] = s;
    __syncthreads();
    for (int off = 1; off < 256; off <<= 1) {
        const int v = (tid >= off) ? buf[tid - off] : 0;
        __syncthreads();
        buf[tid] += v;
        __syncthreads();
    }
    int run = buf[tid] - s;
    #pragma unroll
    for (int i = 0; i < 8; ++i) { offs[tid * 8 + i] = run; run += local[i]; }
    if (tid == 255) offs[NSEG] = run;
}

__global__ void scatter_kernel(const int* __restrict__ ei, const int* __restrict__ offs,
                               int* __restrict__ cursor,
                               const int* __restrict__ rofs, int* __restrict__ rcursor,
                               int* __restrict__ s_te, int* __restrict__ s_seg,
                               int* __restrict__ r_pos)
{
    const int e = blockIdx.x * 256 + threadIdx.x;
    const int b  = ei[e];
    const int hn = ei[NE + e];
    const int tn = ei[2 * NE + e];
    const int rr = ei[3 * NE + e];
    const int seg = b * NN + hn;
    const int pos = offs[seg] + atomicAdd(&cursor[seg], 1);
    s_te[pos]  = tn;
    s_seg[pos] = seg;
    const int rj = atomicAdd(&rcursor[rr], 1);
    r_pos[rofs[rr] + rj] = pos;
}

// ---------------------------------------------------------------------------
// K5: per-relation logits via bf16 MFMA.
// Rows = (edge-in-bucket, head). Qp = gather(Qh) @ Re  (16x16x32 MFMA),
// then fp32 dot with gathered Kh row -> Lg[pos*12+h].
// A-frag: A[m=lane&15][k=(lane>>4)*8+j]; B-frag: B[k=(lane>>4)*8+j][n=lane&15];
// C: col=lane&15, row=(lane>>4)*4+reg.
// ---------------------------------------------------------------------------
__global__ __launch_bounds__(256) void rel_logits(
    const __hip_bfloat16* __restrict__ Qh, const __hip_bfloat16* __restrict__ Kh,
    const float* __restrict__ rel,
    const int* __restrict__ rofs, const int* __restrict__ r_pos,
    const int* __restrict__ s_te, const int* __restrict__ s_seg,
    float* __restrict__ Lg)
{
    const int r = blockIdx.x;
    const int rstart = rofs[r];
    const int rows = (rofs[r + 1] - rstart) * NH;
    const int tid = threadIdx.x;
    const int lane = tid & 63;
    const int wave = tid >> 6;

    __shared__ float ReS[64][65];
    __shared__ int qb[256], kb[256], oi[256];
    __shared__ float QpS[4][16][67];

    {   // stage Re (16 KB, coalesced float4)
        const float* Rg = rel + (size_t)r * 4096;
        for (int i = tid; i < 1024; i += 256) {
            const float4 v = ((const float4*)Rg)[i];
            const int row = i >> 4, c4 = (i & 15) * 4;
            ReS[row][c4] = v.x; ReS[row][c4 + 1] = v.y;
            ReS[row][c4 + 2] = v.z; ReS[row][c4 + 3] = v.w;
        }
    }
    __syncthreads();

    // B fragments: shared by all row tiles of this block
    bf16x8 bfrag[2][4];
    {
        const int q4 = lane >> 4, n = lane & 15;
        #pragma unroll
        for (int ks = 0; ks < 2; ++ks)
            #pragma unroll
            for (int nt = 0; nt < 4; ++nt) {
                bf16x8 f;
                #pragma unroll
                for (int j = 0; j < 8; ++j)
                    f[j] = (short)f2bf(ReS[ks * 32 + q4 * 8 + j][nt * 16 + n]);
                bfrag[ks][nt] = f;
            }
    }

    for (int t0 = blockIdx.y * 256; t0 < rows; t0 += gridDim.y * 256) {
        __syncthreads();   // protect qb/kb/oi from previous tile readers
        {
            const int rowid = t0 + tid;
            if (rowid < rows) {
                const int el = rowid / 12;
                const int h  = rowid - el * 12;
                const int pos = r_pos[rstart + el];
                const int seg = s_seg[pos];
                const int te  = s_te[pos];
                const int b   = seg >> 9;
                qb[tid] = seg * HID + h * 64;
                kb[tid] = (b * NN + te) * HID + h * 64;
                oi[tid] = pos * NH + h;
            } else { qb[tid] = 0; kb[tid] = 0; oi[tid] = -1; }
        }
        __syncthreads();

        // 16 row-groups of 16 rows; each wave takes 4 (uniform trip count)
        for (int g = wave; g < 16; g += 4) {
            const int m = lane & 15, q4 = lane >> 4;
            const int qbase = qb[g * 16 + m];
            f32x4 cfr[4] = {{0,0,0,0},{0,0,0,0},{0,0,0,0},{0,0,0,0}};
            #pragma unroll
            for (int ks = 0; ks < 2; ++ks) {
                const bf16x8 afr = *(const bf16x8*)(Qh + qbase + ks * 32 + q4 * 8);
                #pragma unroll
                for (int nt = 0; nt < 4; ++nt)
                    cfr[nt] = __builtin_amdgcn_mfma_f32_16x16x32_bf16(
                        afr, bfrag[ks][nt], cfr[nt], 0, 0, 0);
            }
            // Qp -> per-wave LDS (stride 67: conflict-free for the read pattern)
            #pragma unroll
            for (int nt = 0; nt < 4; ++nt)
                #pragma unroll
                for (int rg = 0; rg < 4; ++rg)
                    QpS[wave][q4 * 4 + rg][nt * 16 + m] = cfr[nt][rg];
            __syncthreads();   // uniform: all waves do 4 g-iterations

            // dot: row = lane>>2, 16-dim chunk = (lane&3)*16
            const int rw = lane >> 2, ch = (lane & 3) * 16;
            const int rowid2 = g * 16 + rw;
            const int kbase = kb[rowid2];
            const bf16x8 k0 = *(const bf16x8*)(Kh + kbase + ch);
            const bf16x8 k1 = *(const bf16x8*)(Kh + kbase + ch + 8);
            float s = 0.f;
            #pragma unroll
            for (int i = 0; i < 8; ++i) {
                s = fmaf(QpS[wave][rw][ch + i],     bf2f(k0[i]), s);
                s = fmaf(QpS[wave][rw][ch + 8 + i], bf2f(k1[i]), s);
            }
            s += __shfl_xor(s, 1, 64);
            s += __shfl_xor(s, 2, 64);
            if ((lane & 3) == 0) {
                const int o = oi[rowid2];
                if (o >= 0) Lg[o] = s * 0.125f;
            }
            __syncthreads();
        }
    }
}

// ---------------------------------------------------------------------------
// K6: per-segment online softmax + V aggregation (logits precomputed).
// ---------------------------------------------------------------------------
__global__ __launch_bounds__(256) void seg_softmax_agg(
    const float* __restrict__ V, const float* __restrict__ Lg,
    const int* __restrict__ offs, const int* __restrict__ s_te,
    float* __restrict__ out)
{
    const int seg  = blockIdx.x;
    const int tid  = threadIdx.x;
    const int start = offs[seg];
    const int cnt   = offs[seg + 1] - start;
    const int browbase = seg & ~(NN - 1);

    __shared__ float lg[64 * NH];
    __shared__ int   te_s[64];
    __shared__ float mh[NH], lh[NH], ah[NH];

    if (tid < NH) { mh[tid] = -1e30f; lh[tid] = 0.f; }

    float acc0 = 0.f, acc1 = 0.f, acc2 = 0.f;
    const int hh = tid >> 6;
    const int dd = tid & 63;

    for (int c0 = 0; c0 < cnt; c0 += 64) {
        const int cc = min(64, cnt - c0);
        __syncthreads();
        if (tid < cc) te_s[tid] = s_te[start + c0 + tid];
        for (int i = tid; i < cc * NH; i += 256)
            lg[i] = Lg[(start + c0) * NH + i];
        __syncthreads();

        if (tid < NH) {
            const int h = tid;
            float mx = mh[h];
            for (int j = 0; j < cc; ++j) mx = fmaxf(mx, lg[j * NH + h]);
            const float alpha = __expf(mh[h] - mx);
            float ssum = 0.f;
            for (int j = 0; j < cc; ++j) {
                const float p = __expf(lg[j * NH + h] - mx);
                lg[j * NH + h] = p;
                ssum += p;
            }
            lh[h] = lh[h] * alpha + ssum;
            mh[h] = mx;
            ah[h] = alpha;
        }
        __syncthreads();

        const float a0 = ah[hh], a1 = ah[4 + hh], a2 = ah[8 + hh];
        acc0 *= a0; acc1 *= a1; acc2 *= a2;
        for (int j = 0; j < cc; ++j) {
            const int row = browbase + te_s[j];
            const float* __restrict__ Vr = V + (size_t)row * HID + dd;
            acc0 = fmaf(lg[j * NH + hh],     Vr[hh * 64],       acc0);
            acc1 = fmaf(lg[j * NH + 4 + hh], Vr[(4 + hh) * 64], acc1);
            acc2 = fmaf(lg[j * NH + 8 + hh], Vr[(8 + hh) * 64], acc2);
        }
    }
    __syncthreads();

    const float l0 = lh[hh], l1 = lh[4 + hh], l2 = lh[8 + hh];
    float* Yo = out + (size_t)seg * HID;
    Yo[tid]       = (l0 > 0.f) ? acc0 / l0 : 0.f;
    Yo[tid + 256] = (l1 > 0.f) ? acc1 / l1 : 0.f;
    Yo[tid + 512] = (l2 > 0.f) ? acc2 / l2 : 0.f;
}

// ---------------------------------------------------------------------------
extern "C" void kernel_launch(void* const* d_in, const int* in_sizes, int n_in,
                              void* d_out, int out_size, void* d_ws, size_t ws_size,
                              hipStream_t stream)
{
    const float* X   = (const float*)d_in[0];
    const int*   EI  = (const int*)d_in[1];
    const float* Wq  = (const float*)d_in[3];
    const float* bq  = (const float*)d_in[4];
    const float* Wk  = (const float*)d_in[5];
    const float* bk  = (const float*)d_in[6];
    const float* Wv  = (const float*)d_in[7];
    const float* bv  = (const float*)d_in[8];
    const float* rel = (const float*)d_in[9];
    float* out = (float*)d_out;

    char* p = (char*)d_ws;
    __hip_bfloat16* Qh = (__hip_bfloat16*)p;  p += (size_t)NSEG * HID * 2;
    __hip_bfloat16* Kh = (__hip_bfloat16*)p;  p += (size_t)NSEG * HID * 2;
    float* Vb = (float*)p;                    p += (size_t)NSEG * HID * 4;
    float* Lg = (float*)p;                    p += (size_t)NE * NH * 4;
    int* offs    = (int*)p;                   p += 2052 * 4;
    int* rofs    = (int*)p;                   p += 68 * 4;
    int* count   = (int*)p;                   p += NSEG * 4;
    int* cursor  = (int*)p;                   p += NSEG * 4;
    int* rcount  = (int*)p;                   p += NREL * 4;
    int* rcursor = (int*)p;                   p += NREL * 4;
    int* s_te    = (int*)p;                   p += NE * 4;
    int* s_seg   = (int*)p;                   p += NE * 4;
    int* r_pos   = (int*)p;                   p += NE * 4;

    qkv_gemm<<<dim3(HID / 64, (NB * NN) / 64, 3), 256, 0, stream>>>(
        X, Wq, bq, Wk, bk, Wv, bv, Qh, Kh, Vb);

    hipMemsetAsync(count, 0, (2 * NSEG + 2 * NREL) * sizeof(int), stream);
    hist_kernel<<<NE / 256, 256, 0, stream>>>(EI, count, rcount);
    scan_kernel<<<1, 256, 0, stream>>>(count, offs, rcount, rofs);
    scatter_kernel<<<NE / 256, 256, 0, stream>>>(EI, offs, cursor, rofs, rcursor,
                                                 s_te, s_seg, r_pos);

    rel_logits<<<dim3(NREL, 32), 256, 0, stream>>>(Qh, Kh, rel, rofs, r_pos,
                                                   s_te, s_seg, Lg);
    seg_softmax_agg<<<NSEG, 256, 0, stream>>>(Vb, Lg, offs, s_te, out);
}

// Round 3
// 349.283 us; speedup vs baseline: 1.5345x; 1.2426x over previous
//
#include <hip/hip_runtime.h>
#include <hip/hip_bf16.h>

#define NB   4
#define NN   512
#define NH   12
#define DHD  64
#define HID  768
#define NE   65536
#define NSEG 2048
#define NREL 64

typedef short bf16x8 __attribute__((ext_vector_type(8)));
typedef float f32x4  __attribute__((ext_vector_type(4)));

__device__ __forceinline__ unsigned short f2bf(float f) {
    __hip_bfloat16 h = __float2bfloat16(f);
    return *reinterpret_cast<unsigned short*>(&h);
}
__device__ __forceinline__ float bf2f(unsigned short s) {
    return __int_as_float(((int)s) << 16);
}
__device__ __forceinline__ void load_lds16(const void* g, void* l) {
    __builtin_amdgcn_global_load_lds(
        (const __attribute__((address_space(1))) unsigned int*)g,
        (__attribute__((address_space(3))) unsigned int*)l, 16, 0, 0);
}

// ---------------------------------------------------------------------------
// K0: cast X and Wq/Wk/Wv to bf16 (fp32 accumulate happens in MFMA).
// ---------------------------------------------------------------------------
#define NX4 ((2048 * 768) / 4)
#define NW4 ((768 * 768) / 4)
__global__ __launch_bounds__(256) void cast_kernel(
    const float* __restrict__ X, const float* __restrict__ Wq,
    const float* __restrict__ Wk, const float* __restrict__ Wv,
    unsigned short* __restrict__ Xh, unsigned short* __restrict__ Wh)
{
    const int i = blockIdx.x * 256 + threadIdx.x;
    float4 v;
    ushort4* dst;
    if (i < NX4) {
        v = ((const float4*)X)[i];
        dst = &((ushort4*)Xh)[i];
    } else {
        const int j = i - NX4;
        const float* W = (j < NW4) ? Wq : ((j < 2 * NW4) ? Wk : Wv);
        const int jj = (j < NW4) ? j : ((j < 2 * NW4) ? j - NW4 : j - 2 * NW4);
        v = ((const float4*)W)[jj];
        dst = &((ushort4*)Wh)[j];
    }
    ushort4 r;
    r.x = f2bf(v.x); r.y = f2bf(v.y); r.z = f2bf(v.z); r.w = f2bf(v.w);
    *dst = r;
}

// ---------------------------------------------------------------------------
// K1: QKV projection on MFMA. Y = X @ W^T + b, z selects {Q,K,V}.
// 128x128 tile, BK=64, global_load_lds(16B) staging, XOR chunk swizzle so
// ds_read_b128 fragment reads are bank-conflict-free. 4 waves, each 64x64.
// ---------------------------------------------------------------------------
__global__ __launch_bounds__(256) void qkv_mfma(
    const unsigned short* __restrict__ Xh, const unsigned short* __restrict__ Wh,
    const float* __restrict__ bq, const float* __restrict__ bk,
    const float* __restrict__ bv,
    unsigned short* __restrict__ Qh, unsigned short* __restrict__ Kh,
    float* __restrict__ Vo)
{
    const int z = blockIdx.z;
    const unsigned short* W = Wh + (size_t)z * (768 * 768);
    const float* bias = (z == 0) ? bq : ((z == 1) ? bk : bv);

    const int n0 = blockIdx.x * 128;
    const int m0 = blockIdx.y * 128;
    const int tid  = threadIdx.x;
    const int lane = tid & 63;
    const int wave = tid >> 6;
    const int wm = wave >> 1, wn = wave & 1;

    __shared__ unsigned short As[128 * 64];
    __shared__ unsigned short Bs[128 * 64];

    f32x4 acc[4][4];
    #pragma unroll
    for (int a = 0; a < 4; ++a)
        #pragma unroll
        for (int b = 0; b < 4; ++b) acc[a][b] = (f32x4){0.f, 0.f, 0.f, 0.f};

    const int ml = lane & 15;     // m/n within 16-tile
    const int q4 = lane >> 4;     // k-quad

    for (int k0 = 0; k0 < HID; k0 += 64) {
        __syncthreads();
        #pragma unroll
        for (int l = 0; l < 4; ++l) {
            const int idx = (l * 4 + wave) * 64 + lane;   // 0..1023
            const int row = idx >> 3;
            const int kq  = (idx & 7) ^ (row & 7);        // logical 8-elem chunk
            load_lds16(Xh + (size_t)(m0 + row) * HID + k0 + kq * 8,
                       As + (l * 4 + wave) * 512);
            load_lds16(W + (size_t)(n0 + row) * HID + k0 + kq * 8,
                       Bs + (l * 4 + wave) * 512);
        }
        __syncthreads();

        #pragma unroll
        for (int ks = 0; ks < 2; ++ks) {
            bf16x8 af[4], bfr[4];
            #pragma unroll
            for (int t = 0; t < 4; ++t) {
                const int ar = wm * 64 + t * 16 + ml;
                const int ac = (ks * 4 + q4) ^ (ar & 7);
                af[t] = *(const bf16x8*)(As + ar * 64 + ac * 8);
                const int br = wn * 64 + t * 16 + ml;
                const int bc = (ks * 4 + q4) ^ (br & 7);
                bfr[t] = *(const bf16x8*)(Bs + br * 64 + bc * 8);
            }
            #pragma unroll
            for (int mt = 0; mt < 4; ++mt)
                #pragma unroll
                for (int nt = 0; nt < 4; ++nt)
                    acc[mt][nt] = __builtin_amdgcn_mfma_f32_16x16x32_bf16(
                        af[mt], bfr[nt], acc[mt][nt], 0, 0, 0);
        }
    }

    // epilogue: C row = q4*4+rg, col = ml
    #pragma unroll
    for (int nt = 0; nt < 4; ++nt) {
        const int col = n0 + wn * 64 + nt * 16 + ml;
        const float bcol = bias[col];
        #pragma unroll
        for (int mt = 0; mt < 4; ++mt) {
            const int row = m0 + wm * 64 + mt * 16 + q4 * 4;
            #pragma unroll
            for (int rg = 0; rg < 4; ++rg) {
                const float v = acc[mt][nt][rg] + bcol;
                const size_t o = (size_t)(row + rg) * HID + col;
                if (z == 0)      Qh[o] = f2bf(v);
                else if (z == 1) Kh[o] = f2bf(v);
                else             Vo[o] = v;
            }
        }
    }
}

// ---------------------------------------------------------------------------
// CSR build: histogram by segment AND by relation, scan both, scatter both.
// ---------------------------------------------------------------------------
__global__ void hist_kernel(const int* __restrict__ ei,
                            int* __restrict__ count, int* __restrict__ rcount)
{
    const int e = blockIdx.x * 256 + threadIdx.x;
    const int b  = ei[e];
    const int hn = ei[NE + e];
    const int rr = ei[3 * NE + e];
    atomicAdd(&count[b * NN + hn], 1);
    atomicAdd(&rcount[rr], 1);
}

__global__ void scan_kernel(const int* __restrict__ count, int* __restrict__ offs,
                            const int* __restrict__ rcount, int* __restrict__ rofs)
{
    __shared__ int buf[256];
    const int tid = threadIdx.x;
    if (tid == 0) {
        int run = 0;
        for (int i = 0; i < NREL; ++i) { rofs[i] = run; run += rcount[i]; }
        rofs[NREL] = run;
    }
    int local[8];
    int s = 0;
    #pragma unroll
    for (int i = 0; i < 8; ++i) { local[i] = count[tid * 8 + i]; s += local[i]; }
    buf[tid] = s;
    __syncthreads();
    for (int off = 1; off < 256; off <<= 1) {
        const int v = (tid >= off) ? buf[tid - off] : 0;
        __syncthreads();
        buf[tid] += v;
        __syncthreads();
    }
    int run = buf[tid] - s;
    #pragma unroll
    for (int i = 0; i < 8; ++i) { offs[tid * 8 + i] = run; run += local[i]; }
    if (tid == 255) offs[NSEG] = run;
}

__global__ void scatter_kernel(const int* __restrict__ ei, const int* __restrict__ offs,
                               int* __restrict__ cursor,
                               const int* __restrict__ rofs, int* __restrict__ rcursor,
                               int* __restrict__ s_te, int* __restrict__ s_seg,
                               int* __restrict__ r_pos)
{
    const int e = blockIdx.x * 256 + threadIdx.x;
    const int b  = ei[e];
    const int hn = ei[NE + e];
    const int tn = ei[2 * NE + e];
    const int rr = ei[3 * NE + e];
    const int seg = b * NN + hn;
    const int pos = offs[seg] + atomicAdd(&cursor[seg], 1);
    s_te[pos]  = tn;
    s_seg[pos] = seg;
    const int rj = atomicAdd(&rcursor[rr], 1);
    r_pos[rofs[rr] + rj] = pos;
}

// ---------------------------------------------------------------------------
// K5: per-relation logits via bf16 MFMA (Qp = gather(Qh) @ Re, dot with Kh).
// ---------------------------------------------------------------------------
__global__ __launch_bounds__(256) void rel_logits(
    const unsigned short* __restrict__ Qh, const unsigned short* __restrict__ Kh,
    const float* __restrict__ rel,
    const int* __restrict__ rofs, const int* __restrict__ r_pos,
    const int* __restrict__ s_te, const int* __restrict__ s_seg,
    float* __restrict__ Lg)
{
    const int r = blockIdx.x;
    const int rstart = rofs[r];
    const int rows = (rofs[r + 1] - rstart) * NH;
    const int tid = threadIdx.x;
    const int lane = tid & 63;
    const int wave = tid >> 6;

    __shared__ float ReS[64][65];
    __shared__ int qb[256], kb[256], oi[256];
    __shared__ float QpS[4][16][67];

    {
        const float* Rg = rel + (size_t)r * 4096;
        for (int i = tid; i < 1024; i += 256) {
            const float4 v = ((const float4*)Rg)[i];
            const int row = i >> 4, c4 = (i & 15) * 4;
            ReS[row][c4] = v.x; ReS[row][c4 + 1] = v.y;
            ReS[row][c4 + 2] = v.z; ReS[row][c4 + 3] = v.w;
        }
    }
    __syncthreads();

    bf16x8 bfrag[2][4];
    {
        const int q4 = lane >> 4, n = lane & 15;
        #pragma unroll
        for (int ks = 0; ks < 2; ++ks)
            #pragma unroll
            for (int nt = 0; nt < 4; ++nt) {
                bf16x8 f;
                #pragma unroll
                for (int j = 0; j < 8; ++j)
                    f[j] = (short)f2bf(ReS[ks * 32 + q4 * 8 + j][nt * 16 + n]);
                bfrag[ks][nt] = f;
            }
    }

    for (int t0 = blockIdx.y * 256; t0 < rows; t0 += gridDim.y * 256) {
        __syncthreads();
        {
            const int rowid = t0 + tid;
            if (rowid < rows) {
                const int el = rowid / 12;
                const int h  = rowid - el * 12;
                const int pos = r_pos[rstart + el];
                const int seg = s_seg[pos];
                const int te  = s_te[pos];
                const int b   = seg >> 9;
                qb[tid] = seg * HID + h * 64;
                kb[tid] = (b * NN + te) * HID + h * 64;
                oi[tid] = pos * NH + h;
            } else { qb[tid] = 0; kb[tid] = 0; oi[tid] = -1; }
        }
        __syncthreads();

        for (int g = wave; g < 16; g += 4) {
            const int m = lane & 15, q4 = lane >> 4;
            const int qbase = qb[g * 16 + m];
            f32x4 cfr[4] = {{0,0,0,0},{0,0,0,0},{0,0,0,0},{0,0,0,0}};
            #pragma unroll
            for (int ks = 0; ks < 2; ++ks) {
                const bf16x8 afr = *(const bf16x8*)(Qh + qbase + ks * 32 + q4 * 8);
                #pragma unroll
                for (int nt = 0; nt < 4; ++nt)
                    cfr[nt] = __builtin_amdgcn_mfma_f32_16x16x32_bf16(
                        afr, bfrag[ks][nt], cfr[nt], 0, 0, 0);
            }
            #pragma unroll
            for (int nt = 0; nt < 4; ++nt)
                #pragma unroll
                for (int rg = 0; rg < 4; ++rg)
                    QpS[wave][q4 * 4 + rg][nt * 16 + m] = cfr[nt][rg];
            __syncthreads();

            const int rw = lane >> 2, ch = (lane & 3) * 16;
            const int rowid2 = g * 16 + rw;
            const int kbase = kb[rowid2];
            const bf16x8 k0 = *(const bf16x8*)(Kh + kbase + ch);
            const bf16x8 k1 = *(const bf16x8*)(Kh + kbase + ch + 8);
            float s = 0.f;
            #pragma unroll
            for (int i = 0; i < 8; ++i) {
                s = fmaf(QpS[wave][rw][ch + i],     bf2f((unsigned short)k0[i]), s);
                s = fmaf(QpS[wave][rw][ch + 8 + i], bf2f((unsigned short)k1[i]), s);
            }
            s += __shfl_xor(s, 1, 64);
            s += __shfl_xor(s, 2, 64);
            if ((lane & 3) == 0) {
                const int o = oi[rowid2];
                if (o >= 0) Lg[o] = s * 0.125f;
            }
            __syncthreads();
        }
    }
}

// ---------------------------------------------------------------------------
// K6: per-segment online softmax + V aggregation.
// ---------------------------------------------------------------------------
__global__ __launch_bounds__(256) void seg_softmax_agg(
    const float* __restrict__ V, const float* __restrict__ Lg,
    const int* __restrict__ offs, const int* __restrict__ s_te,
    float* __restrict__ out)
{
    const int seg  = blockIdx.x;
    const int tid  = threadIdx.x;
    const int start = offs[seg];
    const int cnt   = offs[seg + 1] - start;
    const int browbase = seg & ~(NN - 1);

    __shared__ float lg[64 * NH];
    __shared__ int   te_s[64];
    __shared__ float mh[NH], lh[NH], ah[NH];

    if (tid < NH) { mh[tid] = -1e30f; lh[tid] = 0.f; }

    float acc0 = 0.f, acc1 = 0.f, acc2 = 0.f;
    const int hh = tid >> 6;
    const int dd = tid & 63;

    for (int c0 = 0; c0 < cnt; c0 += 64) {
        const int cc = min(64, cnt - c0);
        __syncthreads();
        if (tid < cc) te_s[tid] = s_te[start + c0 + tid];
        for (int i = tid; i < cc * NH; i += 256)
            lg[i] = Lg[(start + c0) * NH + i];
        __syncthreads();

        if (tid < NH) {
            const int h = tid;
            float mx = mh[h];
            for (int j = 0; j < cc; ++j) mx = fmaxf(mx, lg[j * NH + h]);
            const float alpha = __expf(mh[h] - mx);
            float ssum = 0.f;
            for (int j = 0; j < cc; ++j) {
                const float p = __expf(lg[j * NH + h] - mx);
                lg[j * NH + h] = p;
                ssum += p;
            }
            lh[h] = lh[h] * alpha + ssum;
            mh[h] = mx;
            ah[h] = alpha;
        }
        __syncthreads();

        const float a0 = ah[hh], a1 = ah[4 + hh], a2 = ah[8 + hh];
        acc0 *= a0; acc1 *= a1; acc2 *= a2;
        for (int j = 0; j < cc; ++j) {
            const int row = browbase + te_s[j];
            const float* __restrict__ Vr = V + (size_t)row * HID + dd;
            acc0 = fmaf(lg[j * NH + hh],     Vr[hh * 64],       acc0);
            acc1 = fmaf(lg[j * NH + 4 + hh], Vr[(4 + hh) * 64], acc1);
            acc2 = fmaf(lg[j * NH + 8 + hh], Vr[(8 + hh) * 64], acc2);
        }
    }
    __syncthreads();

    const float l0 = lh[hh], l1 = lh[4 + hh], l2 = lh[8 + hh];
    float* Yo = out + (size_t)seg * HID;
    Yo[tid]       = (l0 > 0.f) ? acc0 / l0 : 0.f;
    Yo[tid + 256] = (l1 > 0.f) ? acc1 / l1 : 0.f;
    Yo[tid + 512] = (l2 > 0.f) ? acc2 / l2 : 0.f;
}

// ---------------------------------------------------------------------------
extern "C" void kernel_launch(void* const* d_in, const int* in_sizes, int n_in,
                              void* d_out, int out_size, void* d_ws, size_t ws_size,
                              hipStream_t stream)
{
    const float* X   = (const float*)d_in[0];
    const int*   EI  = (const int*)d_in[1];
    const float* Wq  = (const float*)d_in[3];
    const float* bq  = (const float*)d_in[4];
    const float* Wk  = (const float*)d_in[5];
    const float* bk  = (const float*)d_in[6];
    const float* Wv  = (const float*)d_in[7];
    const float* bv  = (const float*)d_in[8];
    const float* rel = (const float*)d_in[9];
    float* out = (float*)d_out;

    char* p = (char*)d_ws;
    unsigned short* Qh = (unsigned short*)p;  p += (size_t)NSEG * HID * 2;
    unsigned short* Kh = (unsigned short*)p;  p += (size_t)NSEG * HID * 2;
    float* Vb = (float*)p;                    p += (size_t)NSEG * HID * 4;
    // Xh (bf16 X) and Lg (f32 logits) have disjoint lifetimes and equal size
    unsigned short* Xh = (unsigned short*)p;
    float* Lg = (float*)p;                    p += (size_t)NE * NH * 4;
    unsigned short* Wh = (unsigned short*)p;  p += (size_t)3 * 768 * 768 * 2;
    int* offs    = (int*)p;                   p += 2052 * 4;
    int* rofs    = (int*)p;                   p += 68 * 4;
    int* count   = (int*)p;                   p += NSEG * 4;
    int* cursor  = (int*)p;                   p += NSEG * 4;
    int* rcount  = (int*)p;                   p += NREL * 4;
    int* rcursor = (int*)p;                   p += NREL * 4;
    int* s_te    = (int*)p;                   p += NE * 4;
    int* s_seg   = (int*)p;                   p += NE * 4;
    int* r_pos   = (int*)p;                   p += NE * 4;

    cast_kernel<<<(NX4 + 3 * NW4 + 255) / 256, 256, 0, stream>>>(
        X, Wq, Wk, Wv, Xh, Wh);
    qkv_mfma<<<dim3(HID / 128, (NB * NN) / 128, 3), 256, 0, stream>>>(
        Xh, Wh, bq, bk, bv, Qh, Kh, Vb);

    hipMemsetAsync(count, 0, (2 * NSEG + 2 * NREL) * sizeof(int), stream);
    hist_kernel<<<NE / 256, 256, 0, stream>>>(EI, count, rcount);
    scan_kernel<<<1, 256, 0, stream>>>(count, offs, rcount, rofs);
    scatter_kernel<<<NE / 256, 256, 0, stream>>>(EI, offs, cursor, rofs, rcursor,
                                                 s_te, s_seg, r_pos);

    rel_logits<<<dim3(NREL, 32), 256, 0, stream>>>(Qh, Kh, rel, rofs, r_pos,
                                                   s_te, s_seg, Lg);
    seg_softmax_agg<<<NSEG, 256, 0, stream>>>(Vb, Lg, offs, s_te, out);
}

// Round 4
// 192.594 us; speedup vs baseline: 2.7830x; 1.8136x over previous
//
#include <hip/hip_runtime.h>
#include <hip/hip_bf16.h>

#define NB   4
#define NN   512
#define NH   12
#define DHD  64
#define HID  768
#define NE   65536
#define NSEG 2048
#define NREL 64
#define NSUB 32          // sub-buckets per relation (atomic contention spread)
#define NRSUB (NREL * NSUB)

typedef short bf16x8 __attribute__((ext_vector_type(8)));
typedef float f32x4  __attribute__((ext_vector_type(4)));

__device__ __forceinline__ unsigned short f2bf(float f) {
    __hip_bfloat16 h = __float2bfloat16(f);
    return *reinterpret_cast<unsigned short*>(&h);
}
__device__ __forceinline__ float bf2f(unsigned short s) {
    return __int_as_float(((int)s) << 16);
}
__device__ __forceinline__ void load_lds16(const void* g, void* l) {
    __builtin_amdgcn_global_load_lds(
        (const __attribute__((address_space(1))) unsigned int*)g,
        (__attribute__((address_space(3))) unsigned int*)l, 16, 0, 0);
}

// ---------------------------------------------------------------------------
// K0: cast X and Wq/Wk/Wv to bf16 (fp32 accumulate happens in MFMA).
// ---------------------------------------------------------------------------
#define NX4 ((2048 * 768) / 4)
#define NW4 ((768 * 768) / 4)
__global__ __launch_bounds__(256) void cast_kernel(
    const float* __restrict__ X, const float* __restrict__ Wq,
    const float* __restrict__ Wk, const float* __restrict__ Wv,
    unsigned short* __restrict__ Xh, unsigned short* __restrict__ Wh)
{
    const int i = blockIdx.x * 256 + threadIdx.x;
    float4 v;
    ushort4* dst;
    if (i < NX4) {
        v = ((const float4*)X)[i];
        dst = &((ushort4*)Xh)[i];
    } else {
        const int j = i - NX4;
        const float* W = (j < NW4) ? Wq : ((j < 2 * NW4) ? Wk : Wv);
        const int jj = (j < NW4) ? j : ((j < 2 * NW4) ? j - NW4 : j - 2 * NW4);
        v = ((const float4*)W)[jj];
        dst = &((ushort4*)Wh)[j];
    }
    ushort4 r;
    r.x = f2bf(v.x); r.y = f2bf(v.y); r.z = f2bf(v.z); r.w = f2bf(v.w);
    *dst = r;
}

// ---------------------------------------------------------------------------
// K1: QKV projection on MFMA. Y = X @ W^T + b, z selects {Q,K,V}.
// ---------------------------------------------------------------------------
__global__ __launch_bounds__(256) void qkv_mfma(
    const unsigned short* __restrict__ Xh, const unsigned short* __restrict__ Wh,
    const float* __restrict__ bq, const float* __restrict__ bk,
    const float* __restrict__ bv,
    unsigned short* __restrict__ Qh, unsigned short* __restrict__ Kh,
    float* __restrict__ Vo)
{
    const int z = blockIdx.z;
    const unsigned short* W = Wh + (size_t)z * (768 * 768);
    const float* bias = (z == 0) ? bq : ((z == 1) ? bk : bv);

    const int n0 = blockIdx.x * 128;
    const int m0 = blockIdx.y * 128;
    const int tid  = threadIdx.x;
    const int lane = tid & 63;
    const int wave = tid >> 6;
    const int wm = wave >> 1, wn = wave & 1;

    __shared__ unsigned short As[128 * 64];
    __shared__ unsigned short Bs[128 * 64];

    f32x4 acc[4][4];
    #pragma unroll
    for (int a = 0; a < 4; ++a)
        #pragma unroll
        for (int b = 0; b < 4; ++b) acc[a][b] = (f32x4){0.f, 0.f, 0.f, 0.f};

    const int ml = lane & 15;
    const int q4 = lane >> 4;

    for (int k0 = 0; k0 < HID; k0 += 64) {
        __syncthreads();
        #pragma unroll
        for (int l = 0; l < 4; ++l) {
            const int idx = (l * 4 + wave) * 64 + lane;
            const int row = idx >> 3;
            const int kq  = (idx & 7) ^ (row & 7);
            load_lds16(Xh + (size_t)(m0 + row) * HID + k0 + kq * 8,
                       As + (l * 4 + wave) * 512);
            load_lds16(W + (size_t)(n0 + row) * HID + k0 + kq * 8,
                       Bs + (l * 4 + wave) * 512);
        }
        __syncthreads();

        #pragma unroll
        for (int ks = 0; ks < 2; ++ks) {
            bf16x8 af[4], bfr[4];
            #pragma unroll
            for (int t = 0; t < 4; ++t) {
                const int ar = wm * 64 + t * 16 + ml;
                const int ac = (ks * 4 + q4) ^ (ar & 7);
                af[t] = *(const bf16x8*)(As + ar * 64 + ac * 8);
                const int br = wn * 64 + t * 16 + ml;
                const int bc = (ks * 4 + q4) ^ (br & 7);
                bfr[t] = *(const bf16x8*)(Bs + br * 64 + bc * 8);
            }
            #pragma unroll
            for (int mt = 0; mt < 4; ++mt)
                #pragma unroll
                for (int nt = 0; nt < 4; ++nt)
                    acc[mt][nt] = __builtin_amdgcn_mfma_f32_16x16x32_bf16(
                        af[mt], bfr[nt], acc[mt][nt], 0, 0, 0);
        }
    }

    #pragma unroll
    for (int nt = 0; nt < 4; ++nt) {
        const int col = n0 + wn * 64 + nt * 16 + ml;
        const float bcol = bias[col];
        #pragma unroll
        for (int mt = 0; mt < 4; ++mt) {
            const int row = m0 + wm * 64 + mt * 16 + q4 * 4;
            #pragma unroll
            for (int rg = 0; rg < 4; ++rg) {
                const float v = acc[mt][nt][rg] + bcol;
                const size_t o = (size_t)(row + rg) * HID + col;
                if (z == 0)      Qh[o] = f2bf(v);
                else if (z == 1) Kh[o] = f2bf(v);
                else             Vo[o] = v;
            }
        }
    }
}

// ---------------------------------------------------------------------------
// CSR build. Relation counters are sub-bucketed 32x to spread atomics.
// ---------------------------------------------------------------------------
__global__ void hist_kernel(const int* __restrict__ ei,
                            int* __restrict__ count, int* __restrict__ rcount2)
{
    const int e = blockIdx.x * 256 + threadIdx.x;
    const int b  = ei[e];
    const int hn = ei[NE + e];
    const int rr = ei[3 * NE + e];
    const int sub = (e >> 8) & (NSUB - 1);
    atomicAdd(&count[b * NN + hn], 1);
    atomicAdd(&rcount2[rr * NSUB + sub], 1);
}

// generic 2048-element exclusive scan (one block, 256 threads x 8 elems)
__global__ void scan_kernel(const int* __restrict__ cnt, int* __restrict__ ofs)
{
    __shared__ int buf[256];
    const int tid = threadIdx.x;
    int local[8];
    int s = 0;
    #pragma unroll
    for (int i = 0; i < 8; ++i) { local[i] = cnt[tid * 8 + i]; s += local[i]; }
    buf[tid] = s;
    __syncthreads();
    for (int off = 1; off < 256; off <<= 1) {
        const int v = (tid >= off) ? buf[tid - off] : 0;
        __syncthreads();
        buf[tid] += v;
        __syncthreads();
    }
    int run = buf[tid] - s;
    #pragma unroll
    for (int i = 0; i < 8; ++i) { ofs[tid * 8 + i] = run; run += local[i]; }
    if (tid == 255) ofs[2048] = run;
}

__global__ void scatter_kernel(const int* __restrict__ ei, const int* __restrict__ offs,
                               int* __restrict__ cursor,
                               const int* __restrict__ rofs2, int* __restrict__ rcursor2,
                               int* __restrict__ s_te, int* __restrict__ s_seg,
                               int* __restrict__ r_pos)
{
    const int e = blockIdx.x * 256 + threadIdx.x;
    const int b  = ei[e];
    const int hn = ei[NE + e];
    const int tn = ei[2 * NE + e];
    const int rr = ei[3 * NE + e];
    const int sub = (e >> 8) & (NSUB - 1);
    const int seg = b * NN + hn;
    const int pos = offs[seg] + atomicAdd(&cursor[seg], 1);
    s_te[pos]  = tn;
    s_seg[pos] = seg;
    const int rb = rr * NSUB + sub;
    const int rj = atomicAdd(&rcursor2[rb], 1);
    r_pos[rofs2[rb] + rj] = pos;
}

// ---------------------------------------------------------------------------
// K5: per-relation logits via bf16 MFMA (Qp = gather(Qh) @ Re, dot with Kh).
// ---------------------------------------------------------------------------
__global__ __launch_bounds__(256) void rel_logits(
    const unsigned short* __restrict__ Qh, const unsigned short* __restrict__ Kh,
    const float* __restrict__ rel,
    const int* __restrict__ rofs2, const int* __restrict__ r_pos,
    const int* __restrict__ s_te, const int* __restrict__ s_seg,
    float* __restrict__ Lg)
{
    const int r = blockIdx.x;
    const int rstart = rofs2[r * NSUB];
    const int rows = (rofs2[(r + 1) * NSUB] - rstart) * NH;
    const int tid = threadIdx.x;
    const int lane = tid & 63;
    const int wave = tid >> 6;

    __shared__ float ReS[64][65];
    __shared__ int qb[256], kb[256], oi[256];
    __shared__ float QpS[4][16][67];

    {
        const float* Rg = rel + (size_t)r * 4096;
        for (int i = tid; i < 1024; i += 256) {
            const float4 v = ((const float4*)Rg)[i];
            const int row = i >> 4, c4 = (i & 15) * 4;
            ReS[row][c4] = v.x; ReS[row][c4 + 1] = v.y;
            ReS[row][c4 + 2] = v.z; ReS[row][c4 + 3] = v.w;
        }
    }
    __syncthreads();

    bf16x8 bfrag[2][4];
    {
        const int q4 = lane >> 4, n = lane & 15;
        #pragma unroll
        for (int ks = 0; ks < 2; ++ks)
            #pragma unroll
            for (int nt = 0; nt < 4; ++nt) {
                bf16x8 f;
                #pragma unroll
                for (int j = 0; j < 8; ++j)
                    f[j] = (short)f2bf(ReS[ks * 32 + q4 * 8 + j][nt * 16 + n]);
                bfrag[ks][nt] = f;
            }
    }

    for (int t0 = blockIdx.y * 256; t0 < rows; t0 += gridDim.y * 256) {
        __syncthreads();
        {
            const int rowid = t0 + tid;
            if (rowid < rows) {
                const int el = rowid / 12;
                const int h  = rowid - el * 12;
                const int pos = r_pos[rstart + el];
                const int seg = s_seg[pos];
                const int te  = s_te[pos];
                const int b   = seg >> 9;
                qb[tid] = seg * HID + h * 64;
                kb[tid] = (b * NN + te) * HID + h * 64;
                oi[tid] = pos * NH + h;
            } else { qb[tid] = 0; kb[tid] = 0; oi[tid] = -1; }
        }
        __syncthreads();

        for (int g = wave; g < 16; g += 4) {
            const int m = lane & 15, q4 = lane >> 4;
            const int qbase = qb[g * 16 + m];
            f32x4 cfr[4] = {{0,0,0,0},{0,0,0,0},{0,0,0,0},{0,0,0,0}};
            #pragma unroll
            for (int ks = 0; ks < 2; ++ks) {
                const bf16x8 afr = *(const bf16x8*)(Qh + qbase + ks * 32 + q4 * 8);
                #pragma unroll
                for (int nt = 0; nt < 4; ++nt)
                    cfr[nt] = __builtin_amdgcn_mfma_f32_16x16x32_bf16(
                        afr, bfrag[ks][nt], cfr[nt], 0, 0, 0);
            }
            #pragma unroll
            for (int nt = 0; nt < 4; ++nt)
                #pragma unroll
                for (int rg = 0; rg < 4; ++rg)
                    QpS[wave][q4 * 4 + rg][nt * 16 + m] = cfr[nt][rg];
            __syncthreads();

            const int rw = lane >> 2, ch = (lane & 3) * 16;
            const int rowid2 = g * 16 + rw;
            const int kbase = kb[rowid2];
            const bf16x8 k0 = *(const bf16x8*)(Kh + kbase + ch);
            const bf16x8 k1 = *(const bf16x8*)(Kh + kbase + ch + 8);
            float s = 0.f;
            #pragma unroll
            for (int i = 0; i < 8; ++i) {
                s = fmaf(QpS[wave][rw][ch + i],     bf2f((unsigned short)k0[i]), s);
                s = fmaf(QpS[wave][rw][ch + 8 + i], bf2f((unsigned short)k1[i]), s);
            }
            s += __shfl_xor(s, 1, 64);
            s += __shfl_xor(s, 2, 64);
            if ((lane & 3) == 0) {
                const int o = oi[rowid2];
                if (o >= 0) Lg[o] = s * 0.125f;
            }
            __syncthreads();
        }
    }
}

// ---------------------------------------------------------------------------
// K6: per-segment online softmax + V aggregation.
// ---------------------------------------------------------------------------
__global__ __launch_bounds__(256) void seg_softmax_agg(
    const float* __restrict__ V, const float* __restrict__ Lg,
    const int* __restrict__ offs, const int* __restrict__ s_te,
    float* __restrict__ out)
{
    const int seg  = blockIdx.x;
    const int tid  = threadIdx.x;
    const int start = offs[seg];
    const int cnt   = offs[seg + 1] - start;
    const int browbase = seg & ~(NN - 1);

    __shared__ float lg[64 * NH];
    __shared__ int   te_s[64];
    __shared__ float mh[NH], lh[NH], ah[NH];

    if (tid < NH) { mh[tid] = -1e30f; lh[tid] = 0.f; }

    float acc0 = 0.f, acc1 = 0.f, acc2 = 0.f;
    const int hh = tid >> 6;
    const int dd = tid & 63;

    for (int c0 = 0; c0 < cnt; c0 += 64) {
        const int cc = min(64, cnt - c0);
        __syncthreads();
        if (tid < cc) te_s[tid] = s_te[start + c0 + tid];
        for (int i = tid; i < cc * NH; i += 256)
            lg[i] = Lg[(start + c0) * NH + i];
        __syncthreads();

        if (tid < NH) {
            const int h = tid;
            float mx = mh[h];
            for (int j = 0; j < cc; ++j) mx = fmaxf(mx, lg[j * NH + h]);
            const float alpha = __expf(mh[h] - mx);
            float ssum = 0.f;
            for (int j = 0; j < cc; ++j) {
                const float p = __expf(lg[j * NH + h] - mx);
                lg[j * NH + h] = p;
                ssum += p;
            }
            lh[h] = lh[h] * alpha + ssum;
            mh[h] = mx;
            ah[h] = alpha;
        }
        __syncthreads();

        const float a0 = ah[hh], a1 = ah[4 + hh], a2 = ah[8 + hh];
        acc0 *= a0; acc1 *= a1; acc2 *= a2;
        for (int j = 0; j < cc; ++j) {
            const int row = browbase + te_s[j];
            const float* __restrict__ Vr = V + (size_t)row * HID + dd;
            acc0 = fmaf(lg[j * NH + hh],     Vr[hh * 64],       acc0);
            acc1 = fmaf(lg[j * NH + 4 + hh], Vr[(4 + hh) * 64], acc1);
            acc2 = fmaf(lg[j * NH + 8 + hh], Vr[(8 + hh) * 64], acc2);
        }
    }
    __syncthreads();

    const float l0 = lh[hh], l1 = lh[4 + hh], l2 = lh[8 + hh];
    float* Yo = out + (size_t)seg * HID;
    Yo[tid]       = (l0 > 0.f) ? acc0 / l0 : 0.f;
    Yo[tid + 256] = (l1 > 0.f) ? acc1 / l1 : 0.f;
    Yo[tid + 512] = (l2 > 0.f) ? acc2 / l2 : 0.f;
}

// ---------------------------------------------------------------------------
extern "C" void kernel_launch(void* const* d_in, const int* in_sizes, int n_in,
                              void* d_out, int out_size, void* d_ws, size_t ws_size,
                              hipStream_t stream)
{
    const float* X   = (const float*)d_in[0];
    const int*   EI  = (const int*)d_in[1];
    const float* Wq  = (const float*)d_in[3];
    const float* bq  = (const float*)d_in[4];
    const float* Wk  = (const float*)d_in[5];
    const float* bk  = (const float*)d_in[6];
    const float* Wv  = (const float*)d_in[7];
    const float* bv  = (const float*)d_in[8];
    const float* rel = (const float*)d_in[9];
    float* out = (float*)d_out;

    char* p = (char*)d_ws;
    unsigned short* Qh = (unsigned short*)p;  p += (size_t)NSEG * HID * 2;
    unsigned short* Kh = (unsigned short*)p;  p += (size_t)NSEG * HID * 2;
    float* Vb = (float*)p;                    p += (size_t)NSEG * HID * 4;
    unsigned short* Xh = (unsigned short*)p;           // overlaps Lg (disjoint life)
    float* Lg = (float*)p;                    p += (size_t)NE * NH * 4;
    unsigned short* Wh = (unsigned short*)p;  p += (size_t)3 * 768 * 768 * 2;
    int* offs     = (int*)p;                  p += 2052 * 4;
    int* rofs2    = (int*)p;                  p += (NRSUB + 4) * 4;
    int* count    = (int*)p;                  p += NSEG * 4;
    int* cursor   = (int*)p;                  p += NSEG * 4;
    int* rcount2  = (int*)p;                  p += NRSUB * 4;
    int* rcursor2 = (int*)p;                  p += NRSUB * 4;
    int* s_te     = (int*)p;                  p += NE * 4;
    int* s_seg    = (int*)p;                  p += NE * 4;
    int* r_pos    = (int*)p;                  p += NE * 4;

    cast_kernel<<<(NX4 + 3 * NW4 + 255) / 256, 256, 0, stream>>>(
        X, Wq, Wk, Wv, Xh, Wh);
    qkv_mfma<<<dim3(HID / 128, (NB * NN) / 128, 3), 256, 0, stream>>>(
        Xh, Wh, bq, bk, bv, Qh, Kh, Vb);

    // count + cursor + rcount2 + rcursor2 are contiguous: one memset
    hipMemsetAsync(count, 0, (2 * NSEG + 2 * NRSUB) * sizeof(int), stream);
    hist_kernel<<<NE / 256, 256, 0, stream>>>(EI, count, rcount2);
    scan_kernel<<<1, 256, 0, stream>>>(count, offs);
    scan_kernel<<<1, 256, 0, stream>>>(rcount2, rofs2);
    scatter_kernel<<<NE / 256, 256, 0, stream>>>(EI, offs, cursor, rofs2, rcursor2,
                                                 s_te, s_seg, r_pos);

    rel_logits<<<dim3(NREL, 32), 256, 0, stream>>>(Qh, Kh, rel, rofs2, r_pos,
                                                   s_te, s_seg, Lg);
    seg_softmax_agg<<<NSEG, 256, 0, stream>>>(Vb, Lg, offs, s_te, out);
}

// Round 5
// 187.978 us; speedup vs baseline: 2.8513x; 1.0246x over previous
//
#include <hip/hip_runtime.h>
#include <hip/hip_bf16.h>

#define NB   4
#define NN   512
#define NH   12
#define DHD  64
#define HID  768
#define NE   65536
#define NSEG 2048
#define NREL 64
#define NSUB 32          // sub-buckets per relation (atomic contention spread)
#define NRSUB (NREL * NSUB)
#define LGS  16          // padded per-edge logit stride (12 heads + 4 pad)

typedef short bf16x8 __attribute__((ext_vector_type(8)));
typedef float f32x4  __attribute__((ext_vector_type(4)));

__device__ __forceinline__ unsigned short f2bf(float f) {
    __hip_bfloat16 h = __float2bfloat16(f);
    return *reinterpret_cast<unsigned short*>(&h);
}
__device__ __forceinline__ float bf2f(unsigned short s) {
    return __int_as_float(((int)s) << 16);
}
__device__ __forceinline__ void load_lds16(const void* g, void* l) {
    __builtin_amdgcn_global_load_lds(
        (const __attribute__((address_space(1))) unsigned int*)g,
        (__attribute__((address_space(3))) unsigned int*)l, 16, 0, 0);
}

// ---------------------------------------------------------------------------
// K0: cast X and Wq/Wk/Wv to bf16 (fp32 accumulate happens in MFMA).
// ---------------------------------------------------------------------------
#define NX4 ((2048 * 768) / 4)
#define NW4 ((768 * 768) / 4)
__global__ __launch_bounds__(256) void cast_kernel(
    const float* __restrict__ X, const float* __restrict__ Wq,
    const float* __restrict__ Wk, const float* __restrict__ Wv,
    unsigned short* __restrict__ Xh, unsigned short* __restrict__ Wh)
{
    const int i = blockIdx.x * 256 + threadIdx.x;
    float4 v;
    ushort4* dst;
    if (i < NX4) {
        v = ((const float4*)X)[i];
        dst = &((ushort4*)Xh)[i];
    } else {
        const int j = i - NX4;
        const float* W = (j < NW4) ? Wq : ((j < 2 * NW4) ? Wk : Wv);
        const int jj = (j < NW4) ? j : ((j < 2 * NW4) ? j - NW4 : j - 2 * NW4);
        v = ((const float4*)W)[jj];
        dst = &((ushort4*)Wh)[j];
    }
    ushort4 r;
    r.x = f2bf(v.x); r.y = f2bf(v.y); r.z = f2bf(v.z); r.w = f2bf(v.w);
    *dst = r;
}

// ---------------------------------------------------------------------------
// K1: QKV projection on MFMA. Y = X @ W^T + b, z selects {Q,K,V}.
// ---------------------------------------------------------------------------
__global__ __launch_bounds__(256) void qkv_mfma(
    const unsigned short* __restrict__ Xh, const unsigned short* __restrict__ Wh,
    const float* __restrict__ bq, const float* __restrict__ bk,
    const float* __restrict__ bv,
    unsigned short* __restrict__ Qh, unsigned short* __restrict__ Kh,
    float* __restrict__ Vo)
{
    const int z = blockIdx.z;
    const unsigned short* W = Wh + (size_t)z * (768 * 768);
    const float* bias = (z == 0) ? bq : ((z == 1) ? bk : bv);

    const int n0 = blockIdx.x * 128;
    const int m0 = blockIdx.y * 128;
    const int tid  = threadIdx.x;
    const int lane = tid & 63;
    const int wave = tid >> 6;
    const int wm = wave >> 1, wn = wave & 1;

    __shared__ unsigned short As[128 * 64];
    __shared__ unsigned short Bs[128 * 64];

    f32x4 acc[4][4];
    #pragma unroll
    for (int a = 0; a < 4; ++a)
        #pragma unroll
        for (int b = 0; b < 4; ++b) acc[a][b] = (f32x4){0.f, 0.f, 0.f, 0.f};

    const int ml = lane & 15;
    const int q4 = lane >> 4;

    for (int k0 = 0; k0 < HID; k0 += 64) {
        __syncthreads();
        #pragma unroll
        for (int l = 0; l < 4; ++l) {
            const int idx = (l * 4 + wave) * 64 + lane;
            const int row = idx >> 3;
            const int kq  = (idx & 7) ^ (row & 7);
            load_lds16(Xh + (size_t)(m0 + row) * HID + k0 + kq * 8,
                       As + (l * 4 + wave) * 512);
            load_lds16(W + (size_t)(n0 + row) * HID + k0 + kq * 8,
                       Bs + (l * 4 + wave) * 512);
        }
        __syncthreads();

        #pragma unroll
        for (int ks = 0; ks < 2; ++ks) {
            bf16x8 af[4], bfr[4];
            #pragma unroll
            for (int t = 0; t < 4; ++t) {
                const int ar = wm * 64 + t * 16 + ml;
                const int ac = (ks * 4 + q4) ^ (ar & 7);
                af[t] = *(const bf16x8*)(As + ar * 64 + ac * 8);
                const int br = wn * 64 + t * 16 + ml;
                const int bc = (ks * 4 + q4) ^ (br & 7);
                bfr[t] = *(const bf16x8*)(Bs + br * 64 + bc * 8);
            }
            #pragma unroll
            for (int mt = 0; mt < 4; ++mt)
                #pragma unroll
                for (int nt = 0; nt < 4; ++nt)
                    acc[mt][nt] = __builtin_amdgcn_mfma_f32_16x16x32_bf16(
                        af[mt], bfr[nt], acc[mt][nt], 0, 0, 0);
        }
    }

    #pragma unroll
    for (int nt = 0; nt < 4; ++nt) {
        const int col = n0 + wn * 64 + nt * 16 + ml;
        const float bcol = bias[col];
        #pragma unroll
        for (int mt = 0; mt < 4; ++mt) {
            const int row = m0 + wm * 64 + mt * 16 + q4 * 4;
            #pragma unroll
            for (int rg = 0; rg < 4; ++rg) {
                const float v = acc[mt][nt][rg] + bcol;
                const size_t o = (size_t)(row + rg) * HID + col;
                if (z == 0)      Qh[o] = f2bf(v);
                else if (z == 1) Kh[o] = f2bf(v);
                else             Vo[o] = v;
            }
        }
    }
}

// ---------------------------------------------------------------------------
// CSR build. Relation counters are sub-bucketed 32x to spread atomics.
// ---------------------------------------------------------------------------
__global__ void hist_kernel(const int* __restrict__ ei,
                            int* __restrict__ count, int* __restrict__ rcount2)
{
    const int e = blockIdx.x * 256 + threadIdx.x;
    const int b  = ei[e];
    const int hn = ei[NE + e];
    const int rr = ei[3 * NE + e];
    const int sub = (e >> 8) & (NSUB - 1);
    atomicAdd(&count[b * NN + hn], 1);
    atomicAdd(&rcount2[rr * NSUB + sub], 1);
}

// generic 2048-element exclusive scan (one block, 256 threads x 8 elems)
__global__ void scan_kernel(const int* __restrict__ cnt, int* __restrict__ ofs)
{
    __shared__ int buf[256];
    const int tid = threadIdx.x;
    int local[8];
    int s = 0;
    #pragma unroll
    for (int i = 0; i < 8; ++i) { local[i] = cnt[tid * 8 + i]; s += local[i]; }
    buf[tid] = s;
    __syncthreads();
    for (int off = 1; off < 256; off <<= 1) {
        const int v = (tid >= off) ? buf[tid - off] : 0;
        __syncthreads();
        buf[tid] += v;
        __syncthreads();
    }
    int run = buf[tid] - s;
    #pragma unroll
    for (int i = 0; i < 8; ++i) { ofs[tid * 8 + i] = run; run += local[i]; }
    if (tid == 255) ofs[2048] = run;
}

__global__ void scatter_kernel(const int* __restrict__ ei, const int* __restrict__ offs,
                               int* __restrict__ cursor,
                               const int* __restrict__ rofs2, int* __restrict__ rcursor2,
                               int* __restrict__ s_te, int* __restrict__ s_seg,
                               int* __restrict__ r_pos)
{
    const int e = blockIdx.x * 256 + threadIdx.x;
    const int b  = ei[e];
    const int hn = ei[NE + e];
    const int tn = ei[2 * NE + e];
    const int rr = ei[3 * NE + e];
    const int sub = (e >> 8) & (NSUB - 1);
    const int seg = b * NN + hn;
    const int pos = offs[seg] + atomicAdd(&cursor[seg], 1);
    s_te[pos]  = tn;
    s_seg[pos] = seg;
    const int rb = rr * NSUB + sub;
    const int rj = atomicAdd(&rcursor2[rb], 1);
    r_pos[rofs2[rb] + rj] = pos;
}

// ---------------------------------------------------------------------------
// K5: per-relation logits via bf16 MFMA (Qp = gather(Qh) @ Re, dot with Kh).
// QpS is wave-private -> NO __syncthreads in the g-loop (compiler lgkmcnt
// handles wave-internal LDS write->read ordering). Lg padded stride 16.
// ---------------------------------------------------------------------------
__global__ __launch_bounds__(256) void rel_logits(
    const unsigned short* __restrict__ Qh, const unsigned short* __restrict__ Kh,
    const float* __restrict__ rel,
    const int* __restrict__ rofs2, const int* __restrict__ r_pos,
    const int* __restrict__ s_te, const int* __restrict__ s_seg,
    float* __restrict__ Lg)
{
    const int r = blockIdx.x;
    const int rstart = rofs2[r * NSUB];
    const int rows = (rofs2[(r + 1) * NSUB] - rstart) * NH;
    const int tid = threadIdx.x;
    const int lane = tid & 63;
    const int wave = tid >> 6;

    __shared__ float ReS[64][65];
    __shared__ int qb[256], kb[256], oi[256];
    __shared__ float QpS[4][16][67];

    {
        const float* Rg = rel + (size_t)r * 4096;
        for (int i = tid; i < 1024; i += 256) {
            const float4 v = ((const float4*)Rg)[i];
            const int row = i >> 4, c4 = (i & 15) * 4;
            ReS[row][c4] = v.x; ReS[row][c4 + 1] = v.y;
            ReS[row][c4 + 2] = v.z; ReS[row][c4 + 3] = v.w;
        }
    }
    __syncthreads();

    bf16x8 bfrag[2][4];
    {
        const int q4 = lane >> 4, n = lane & 15;
        #pragma unroll
        for (int ks = 0; ks < 2; ++ks)
            #pragma unroll
            for (int nt = 0; nt < 4; ++nt) {
                bf16x8 f;
                #pragma unroll
                for (int j = 0; j < 8; ++j)
                    f[j] = (short)f2bf(ReS[ks * 32 + q4 * 8 + j][nt * 16 + n]);
                bfrag[ks][nt] = f;
            }
    }

    for (int t0 = blockIdx.y * 256; t0 < rows; t0 += gridDim.y * 256) {
        __syncthreads();   // protect qb/kb/oi from previous tile's readers
        {
            const int rowid = t0 + tid;
            if (rowid < rows) {
                const int el = rowid / 12;
                const int h  = rowid - el * 12;
                const int pos = r_pos[rstart + el];
                const int seg = s_seg[pos];
                const int te  = s_te[pos];
                const int b   = seg >> 9;
                qb[tid] = seg * HID + h * 64;
                kb[tid] = (b * NN + te) * HID + h * 64;
                oi[tid] = pos * LGS + h;
            } else { qb[tid] = 0; kb[tid] = 0; oi[tid] = -1; }
        }
        __syncthreads();

        for (int g = wave; g < 16; g += 4) {
            const int m = lane & 15, q4 = lane >> 4;
            const int qbase = qb[g * 16 + m];
            f32x4 cfr[4] = {{0,0,0,0},{0,0,0,0},{0,0,0,0},{0,0,0,0}};
            #pragma unroll
            for (int ks = 0; ks < 2; ++ks) {
                const bf16x8 afr = *(const bf16x8*)(Qh + qbase + ks * 32 + q4 * 8);
                #pragma unroll
                for (int nt = 0; nt < 4; ++nt)
                    cfr[nt] = __builtin_amdgcn_mfma_f32_16x16x32_bf16(
                        afr, bfrag[ks][nt], cfr[nt], 0, 0, 0);
            }
            #pragma unroll
            for (int nt = 0; nt < 4; ++nt)
                #pragma unroll
                for (int rg = 0; rg < 4; ++rg)
                    QpS[wave][q4 * 4 + rg][nt * 16 + m] = cfr[nt][rg];
            // wave-private LDS: no barrier needed

            const int rw = lane >> 2, ch = (lane & 3) * 16;
            const int rowid2 = g * 16 + rw;
            const int kbase = kb[rowid2];
            const bf16x8 k0 = *(const bf16x8*)(Kh + kbase + ch);
            const bf16x8 k1 = *(const bf16x8*)(Kh + kbase + ch + 8);
            float s = 0.f;
            #pragma unroll
            for (int i = 0; i < 8; ++i) {
                s = fmaf(QpS[wave][rw][ch + i],     bf2f((unsigned short)k0[i]), s);
                s = fmaf(QpS[wave][rw][ch + 8 + i], bf2f((unsigned short)k1[i]), s);
            }
            s += __shfl_xor(s, 1, 64);
            s += __shfl_xor(s, 2, 64);
            if ((lane & 3) == 0) {
                const int o = oi[rowid2];
                if (o >= 0) Lg[o] = s * 0.125f;
            }
        }
    }
}

// ---------------------------------------------------------------------------
// K6: per-segment online softmax + V aggregation.
// Wave w owns heads {w, 4+w, 8+w}. Softmax fully in-register via 64-lane
// shfl butterflies; p stored to wave-private LDS slab for broadcast reads.
// ---------------------------------------------------------------------------
__global__ __launch_bounds__(256) void seg_softmax_agg(
    const float* __restrict__ V, const float* __restrict__ Lg,
    const int* __restrict__ offs, const int* __restrict__ s_te,
    float* __restrict__ out)
{
    const int seg  = blockIdx.x;
    const int tid  = threadIdx.x;
    const int lane = tid & 63;
    const int w    = tid >> 6;
    const int start = offs[seg];
    const int cnt   = offs[seg + 1] - start;
    const int browbase = seg & ~(NN - 1);

    __shared__ int   te_s[64];
    __shared__ float pv[4][3][64];

    float m0 = -1e30f, m1 = -1e30f, m2 = -1e30f;
    float l0 = 0.f, l1 = 0.f, l2 = 0.f;
    float acc0 = 0.f, acc1 = 0.f, acc2 = 0.f;

    for (int c0 = 0; c0 < cnt; c0 += 64) {
        const int cc = min(64, cnt - c0);
        __syncthreads();
        if (tid < cc) te_s[tid] = s_te[start + c0 + tid];
        __syncthreads();

        float g0 = -1e30f, g1 = -1e30f, g2 = -1e30f;
        if (lane < cc) {
            const float* Lp = Lg + (size_t)(start + c0 + lane) * LGS;
            g0 = Lp[w]; g1 = Lp[4 + w]; g2 = Lp[8 + w];
        }
        float x0 = g0, x1 = g1, x2 = g2;
        #pragma unroll
        for (int o = 1; o < 64; o <<= 1) {
            x0 = fmaxf(x0, __shfl_xor(x0, o, 64));
            x1 = fmaxf(x1, __shfl_xor(x1, o, 64));
            x2 = fmaxf(x2, __shfl_xor(x2, o, 64));
        }
        const float nm0 = fmaxf(m0, x0), nm1 = fmaxf(m1, x1), nm2 = fmaxf(m2, x2);
        const float a0 = __expf(m0 - nm0), a1 = __expf(m1 - nm1), a2 = __expf(m2 - nm2);
        float p0 = (lane < cc) ? __expf(g0 - nm0) : 0.f;
        float p1 = (lane < cc) ? __expf(g1 - nm1) : 0.f;
        float p2 = (lane < cc) ? __expf(g2 - nm2) : 0.f;
        float s0 = p0, s1 = p1, s2 = p2;
        #pragma unroll
        for (int o = 1; o < 64; o <<= 1) {
            s0 += __shfl_xor(s0, o, 64);
            s1 += __shfl_xor(s1, o, 64);
            s2 += __shfl_xor(s2, o, 64);
        }
        l0 = l0 * a0 + s0; l1 = l1 * a1 + s1; l2 = l2 * a2 + s2;
        m0 = nm0; m1 = nm1; m2 = nm2;
        pv[w][0][lane] = p0; pv[w][1][lane] = p1; pv[w][2][lane] = p2;
        // wave-private LDS: no barrier needed

        acc0 *= a0; acc1 *= a1; acc2 *= a2;
        for (int j = 0; j < cc; ++j) {
            const float* __restrict__ Vr =
                V + (size_t)(browbase + te_s[j]) * HID + lane;
            acc0 = fmaf(pv[w][0][j], Vr[w * 64],       acc0);
            acc1 = fmaf(pv[w][1][j], Vr[(4 + w) * 64], acc1);
            acc2 = fmaf(pv[w][2][j], Vr[(8 + w) * 64], acc2);
        }
    }

    float* Yo = out + (size_t)seg * HID;
    Yo[tid]       = (l0 > 0.f) ? acc0 / l0 : 0.f;
    Yo[tid + 256] = (l1 > 0.f) ? acc1 / l1 : 0.f;
    Yo[tid + 512] = (l2 > 0.f) ? acc2 / l2 : 0.f;
}

// ---------------------------------------------------------------------------
extern "C" void kernel_launch(void* const* d_in, const int* in_sizes, int n_in,
                              void* d_out, int out_size, void* d_ws, size_t ws_size,
                              hipStream_t stream)
{
    const float* X   = (const float*)d_in[0];
    const int*   EI  = (const int*)d_in[1];
    const float* Wq  = (const float*)d_in[3];
    const float* bq  = (const float*)d_in[4];
    const float* Wk  = (const float*)d_in[5];
    const float* bk  = (const float*)d_in[6];
    const float* Wv  = (const float*)d_in[7];
    const float* bv  = (const float*)d_in[8];
    const float* rel = (const float*)d_in[9];
    float* out = (float*)d_out;

    char* p = (char*)d_ws;
    unsigned short* Qh = (unsigned short*)p;  p += (size_t)NSEG * HID * 2;
    unsigned short* Kh = (unsigned short*)p;  p += (size_t)NSEG * HID * 2;
    float* Vb = (float*)p;                    p += (size_t)NSEG * HID * 4;
    unsigned short* Xh = (unsigned short*)p;           // overlaps Lg (disjoint life)
    float* Lg = (float*)p;                    p += (size_t)NE * LGS * 4;
    unsigned short* Wh = (unsigned short*)p;  p += (size_t)3 * 768 * 768 * 2;
    int* offs     = (int*)p;                  p += 2052 * 4;
    int* rofs2    = (int*)p;                  p += (NRSUB + 4) * 4;
    int* count    = (int*)p;                  p += NSEG * 4;
    int* cursor   = (int*)p;                  p += NSEG * 4;
    int* rcount2  = (int*)p;                  p += NRSUB * 4;
    int* rcursor2 = (int*)p;                  p += NRSUB * 4;
    int* s_te     = (int*)p;                  p += NE * 4;
    int* s_seg    = (int*)p;                  p += NE * 4;
    int* r_pos    = (int*)p;                  p += NE * 4;

    cast_kernel<<<(NX4 + 3 * NW4 + 255) / 256, 256, 0, stream>>>(
        X, Wq, Wk, Wv, Xh, Wh);
    qkv_mfma<<<dim3(HID / 128, (NB * NN) / 128, 3), 256, 0, stream>>>(
        Xh, Wh, bq, bk, bv, Qh, Kh, Vb);

    // count + cursor + rcount2 + rcursor2 are contiguous: one memset
    hipMemsetAsync(count, 0, (2 * NSEG + 2 * NRSUB) * sizeof(int), stream);
    hist_kernel<<<NE / 256, 256, 0, stream>>>(EI, count, rcount2);
    scan_kernel<<<1, 256, 0, stream>>>(count, offs);
    scan_kernel<<<1, 256, 0, stream>>>(rcount2, rofs2);
    scatter_kernel<<<NE / 256, 256, 0, stream>>>(EI, offs, cursor, rofs2, rcursor2,
                                                 s_te, s_seg, r_pos);

    rel_logits<<<dim3(NREL, 32), 256, 0, stream>>>(Qh, Kh, rel, rofs2, r_pos,
                                                   s_te, s_seg, Lg);
    seg_softmax_agg<<<NSEG, 256, 0, stream>>>(Vb, Lg, offs, s_te, out);
}